// Round 1
// baseline (8167.497 us; speedup 1.0000x reference)
//
#include <hip/hip_runtime.h>
#include <math.h>

#define Bb 64
#define Tt 2048
#define Ii 256
#define Hh 512
#define Oo 256

using f32x4  = __attribute__((ext_vector_type(4))) float;
using bf16x8 = __attribute__((ext_vector_type(8))) short;
using u32x4  = __attribute__((ext_vector_type(4))) unsigned int;

__device__ __forceinline__ unsigned short f2bf(float f) {
    union { float f; unsigned u; } v; v.f = f;
    unsigned r = v.u + 0x7fffu + ((v.u >> 16) & 1u);
    return (unsigned short)(r >> 16);
}
__device__ __forceinline__ float bf2f(unsigned short b) {
    union { unsigned u; float f; } v; v.u = ((unsigned)b) << 16;
    return v.f;
}
__device__ __forceinline__ float tanh_fast(float x) {
    float e = __expf(2.0f * x);
    return 1.0f - 2.0f / (e + 1.0f);
}
__device__ __forceinline__ void cvt16(unsigned short* dst, const float* s) {
    u32x4 a, b;
#pragma unroll
    for (int i = 0; i < 4; ++i)
        a[i] = (unsigned)f2bf(s[2*i]) | ((unsigned)f2bf(s[2*i+1]) << 16);
#pragma unroll
    for (int i = 0; i < 4; ++i)
        b[i] = (unsigned)f2bf(s[8+2*i]) | ((unsigned)f2bf(s[8+2*i+1]) << 16);
    *(u32x4*)dst = a;
    *(u32x4*)(dst + 8) = b;
}

// ---------------- flags init (re-run every launch: determinism under replay) --
__global__ void k_init(int* flags) {
    if (threadIdx.x < 16) flags[threadIdx.x] = 0;
}

// ---------------- Phase 1: xp[t*64+b][h] = x[b,t,:]·W_ih[h,:] + b_ih + b_hh ---
__global__ __launch_bounds__(256) void k_xproj(
    const float* __restrict__ x, const float* __restrict__ W_ih,
    const float* __restrict__ b_ih, const float* __restrict__ b_hh,
    unsigned short* __restrict__ buf)
{
    __shared__ __align__(16) unsigned short Asm[128][40];  // +8 pad: bank spread
    __shared__ __align__(16) unsigned short Bsm[128][40];
    __shared__ float bias_s[128];

    const int tid = threadIdx.x;
    const int lane = tid & 63, wv = tid >> 6;
    const int l15 = lane & 15, lhi = lane >> 4;
    const int r0 = blockIdx.x * 128, c0 = blockIdx.y * 128;

    if (tid < 128) { int c = c0 + tid; bias_s[tid] = b_ih[c] + b_hh[c]; }

    const int srow = tid >> 1, sks = (tid & 1) * 16;
    const int Rr = r0 + srow;
    const float* asrc = x + ((size_t)(Rr & 63) * Tt + (Rr >> 6)) * Ii + sks;
    const float* bsrc = W_ih + (size_t)(c0 + srow) * Ii + sks;

    const int m0 = (wv >> 1) * 64, n0 = (wv & 1) * 64;

    f32x4 acc[4][4];
#pragma unroll
    for (int i = 0; i < 4; ++i)
#pragma unroll
        for (int j = 0; j < 4; ++j) acc[i][j] = (f32x4){0.f,0.f,0.f,0.f};

    for (int kk = 0; kk < Ii/32; ++kk) {
        __syncthreads();
        {
            float s[16];
#pragma unroll
            for (int q = 0; q < 4; ++q) *(f32x4*)&s[q*4] = *(const f32x4*)(asrc + kk*32 + q*4);
            cvt16(&Asm[srow][sks], s);
#pragma unroll
            for (int q = 0; q < 4; ++q) *(f32x4*)&s[q*4] = *(const f32x4*)(bsrc + kk*32 + q*4);
            cvt16(&Bsm[srow][sks], s);
        }
        __syncthreads();
        bf16x8 af[4], bfr[4];
#pragma unroll
        for (int mi = 0; mi < 4; ++mi) af[mi]  = *(const bf16x8*)&Asm[m0 + mi*16 + l15][lhi*8];
#pragma unroll
        for (int ni = 0; ni < 4; ++ni) bfr[ni] = *(const bf16x8*)&Bsm[n0 + ni*16 + l15][lhi*8];
#pragma unroll
        for (int mi = 0; mi < 4; ++mi)
#pragma unroll
            for (int ni = 0; ni < 4; ++ni)
                acc[mi][ni] = __builtin_amdgcn_mfma_f32_16x16x32_bf16(af[mi], bfr[ni], acc[mi][ni], 0, 0, 0);
    }
#pragma unroll
    for (int mi = 0; mi < 4; ++mi)
#pragma unroll
        for (int ni = 0; ni < 4; ++ni) {
            int n = n0 + ni*16 + l15;
            float bias = bias_s[n];
#pragma unroll
            for (int ri = 0; ri < 4; ++ri) {
                int m = m0 + mi*16 + lhi*4 + ri;
                buf[(size_t)(r0 + m) * Hh + (c0 + n)] = f2bf(acc[mi][ni][ri] + bias);
            }
        }
}

// ---------------- Phase 2: recurrence --------------------------------------
// 16 blocks = 4 batch-groups (16 rows) x 4 j-slices (128 cols).
// W_hh slice lives in registers as MFMA B-frags (Wf0/Wf1: 128 VGPR/lane).
// Cross-block h exchange via agent-scope (sc1) atomics + per-block flags.
__global__ __launch_bounds__(256, 1) void k_rnn(
    const float* __restrict__ W_hh, unsigned short* buf, int* flags)
{
    __shared__ __align__(16) char hsm[16 * 1024];           // 16 x 512 bf16, XOR-swizzled
    __shared__ __align__(16) unsigned short osm[16 * 128];  // own out slice

    const int tid = threadIdx.x;
    const int lane = tid & 63, wv = tid >> 6;
    const int l15 = lane & 15, lhi = lane >> 4;
    const int bid = blockIdx.x;
    const int g = bid >> 2, p = bid & 3;

    // ---- load persistent W fragments: wave wv owns j-tiles p*128+wv*32+{0,16}
    bf16x8 Wf0[16], Wf1[16];
    {
        const float* w0 = W_hh + (size_t)(p*128 + wv*32 + l15) * Hh + lhi*8;
        const float* w1 = w0 + (size_t)16 * Hh;
#pragma unroll
        for (int kt = 0; kt < 16; ++kt) {
            float s[8]; bf16x8 v;
            *(f32x4*)&s[0] = *(const f32x4*)(w0 + kt*32);
            *(f32x4*)&s[4] = *(const f32x4*)(w0 + kt*32 + 4);
#pragma unroll
            for (int i = 0; i < 8; ++i) v[i] = (short)f2bf(s[i]);
            Wf0[kt] = v;
            *(f32x4*)&s[0] = *(const f32x4*)(w1 + kt*32);
            *(f32x4*)&s[4] = *(const f32x4*)(w1 + kt*32 + 4);
#pragma unroll
            for (int i = 0; i < 8; ++i) v[i] = (short)f2bf(s[i]);
            Wf1[kt] = v;
        }
    }

    for (int t = 0; t < Tt; ++t) {
        const size_t rowbase = (size_t)t * Bb + g*16;

        // prefetch xp tile (own region of buf[t]; written by k_xproj, not yet overwritten)
        unsigned short xpr[2][4];
#pragma unroll
        for (int nt = 0; nt < 2; ++nt) {
            int j = p*128 + wv*32 + nt*16 + l15;
#pragma unroll
            for (int ri = 0; ri < 4; ++ri)
                xpr[nt][ri] = buf[(rowbase + lhi*4 + ri) * Hh + j];
        }

        f32x4 acc0 = {0.f,0.f,0.f,0.f}, acc1 = {0.f,0.f,0.f,0.f};
        if (t > 0) {
            if (tid < 3) {  // wait for the 3 partner slices of h_{t-1}
                int q = tid + (tid >= p ? 1 : 0);
                while (__hip_atomic_load(&flags[g*4 + q], __ATOMIC_ACQUIRE,
                                         __HIP_MEMORY_SCOPE_AGENT) < t) { }
            }
            __syncthreads();
            // stage h_{t-1}[16 x 512] -> LDS (XOR-swizzle rows to kill 16-way conflicts)
            unsigned long long* src =
                (unsigned long long*)(buf + ((size_t)(t-1) * Bb + g*16) * Hh);
#pragma unroll
            for (int it = 0; it < 8; ++it) {
                int u = tid + it*256;                  // 2048 u64 = 16KB
                unsigned long long v = __hip_atomic_load(src + u, __ATOMIC_RELAXED,
                                                         __HIP_MEMORY_SCOPE_AGENT);
                int row = u >> 7;
                int byt = (row << 10) + ((u & 127) << 3);
                *(unsigned long long*)(hsm + (byt ^ ((row & 7) << 4))) = v;
            }
            __syncthreads();
#pragma unroll
            for (int kt = 0; kt < 16; ++kt) {
                int byt = (l15 << 10) + kt*64 + (lhi << 4);
                bf16x8 af = *(const bf16x8*)(hsm + (byt ^ ((l15 & 7) << 4)));
                acc0 = __builtin_amdgcn_mfma_f32_16x16x32_bf16(af, Wf0[kt], acc0, 0, 0, 0);
                acc1 = __builtin_amdgcn_mfma_f32_16x16x32_bf16(af, Wf1[kt], acc1, 0, 0, 0);
            }
        }
        // epilogue: h = tanh(acc + xp) -> osm
#pragma unroll
        for (int nt = 0; nt < 2; ++nt) {
            int jl = wv*32 + nt*16 + l15;
#pragma unroll
            for (int ri = 0; ri < 4; ++ri) {
                float v = (nt ? acc1[ri] : acc0[ri]) + bf2f(xpr[nt][ri]);
                osm[(lhi*4 + ri)*128 + jl] = f2bf(tanh_fast(v));
            }
        }
        __syncthreads();
        // publish own h slice into buf[t] (in-place over consumed xp), sc1 stores
#pragma unroll
        for (int it = 0; it < 2; ++it) {
            int u = tid + it*256;                      // 512 u64 = 4KB
            int row = u >> 5, c = u & 31;
            unsigned long long v = *(const unsigned long long*)&osm[row*128 + (c << 2)];
            __hip_atomic_store((unsigned long long*)(buf + (rowbase + row)*Hh + p*128) + c,
                               v, __ATOMIC_RELAXED, __HIP_MEMORY_SCOPE_AGENT);
        }
        __syncthreads();   // drains vmcnt: all slice stores complete before flag
        if (tid == 0)
            __hip_atomic_store(&flags[bid], t + 1, __ATOMIC_RELEASE,
                               __HIP_MEMORY_SCOPE_AGENT);
    }
}

// ---------------- Phase 3: out[b*T+t][o] = outs[t,b,:]·W_fc[o,:] + b_fc -----
__global__ __launch_bounds__(256) void k_fc(
    const unsigned short* __restrict__ buf, const float* __restrict__ W_fc,
    const float* __restrict__ b_fc, float* __restrict__ out)
{
    __shared__ __align__(16) unsigned short Asm[128][40];
    __shared__ __align__(16) unsigned short Bsm[128][40];
    __shared__ float bias_s[128];

    const int tid = threadIdx.x;
    const int lane = tid & 63, wv = tid >> 6;
    const int l15 = lane & 15, lhi = lane >> 4;
    const int r0 = blockIdx.x * 128, c0 = blockIdx.y * 128;

    if (tid < 128) bias_s[tid] = b_fc[c0 + tid];

    const int srow = tid >> 1, sks = (tid & 1) * 16;
    const unsigned short* asrc = buf + (size_t)(r0 + srow) * Hh + sks;
    const float* bsrc = W_fc + (size_t)(c0 + srow) * Hh + sks;

    const int m0 = (wv >> 1) * 64, n0 = (wv & 1) * 64;

    f32x4 acc[4][4];
#pragma unroll
    for (int i = 0; i < 4; ++i)
#pragma unroll
        for (int j = 0; j < 4; ++j) acc[i][j] = (f32x4){0.f,0.f,0.f,0.f};

    for (int kk = 0; kk < Hh/32; ++kk) {
        __syncthreads();
        {
            const unsigned short* pa = asrc + kk*32;
            *(u32x4*)&Asm[srow][sks]     = *(const u32x4*)pa;
            *(u32x4*)&Asm[srow][sks + 8] = *(const u32x4*)(pa + 8);
            float s[16];
#pragma unroll
            for (int q = 0; q < 4; ++q) *(f32x4*)&s[q*4] = *(const f32x4*)(bsrc + kk*32 + q*4);
            cvt16(&Bsm[srow][sks], s);
        }
        __syncthreads();
        bf16x8 af[4], bfr[4];
#pragma unroll
        for (int mi = 0; mi < 4; ++mi) af[mi]  = *(const bf16x8*)&Asm[m0 + mi*16 + l15][lhi*8];
#pragma unroll
        for (int ni = 0; ni < 4; ++ni) bfr[ni] = *(const bf16x8*)&Bsm[n0 + ni*16 + l15][lhi*8];
#pragma unroll
        for (int mi = 0; mi < 4; ++mi)
#pragma unroll
            for (int ni = 0; ni < 4; ++ni)
                acc[mi][ni] = __builtin_amdgcn_mfma_f32_16x16x32_bf16(af[mi], bfr[ni], acc[mi][ni], 0, 0, 0);
    }
#pragma unroll
    for (int mi = 0; mi < 4; ++mi)
#pragma unroll
        for (int ni = 0; ni < 4; ++ni) {
            int n = n0 + ni*16 + l15;
            float bias = bias_s[n];
#pragma unroll
            for (int ri = 0; ri < 4; ++ri) {
                int m = m0 + mi*16 + lhi*4 + ri;
                int R = r0 + m;                         // buf row = t*64+b
                int bb = R & 63, tt = R >> 6;
                out[((size_t)bb * Tt + tt) * Oo + (c0 + n)] = acc[mi][ni][ri] + bias;
            }
        }
}

// ---------------- Phase 4: hidden = h_{T-1} --------------------------------
__global__ void k_hid(const unsigned short* __restrict__ buf, float* __restrict__ hid) {
    int i = blockIdx.x * blockDim.x + threadIdx.x;
    if (i < Bb * Hh) {
        int b = i >> 9, j = i & 511;
        hid[i] = bf2f(buf[((size_t)(Tt - 1) * Bb + b) * Hh + j]);
    }
}

extern "C" void kernel_launch(void* const* d_in, const int* in_sizes, int n_in,
                              void* d_out, int out_size, void* d_ws, size_t ws_size,
                              hipStream_t stream) {
    (void)in_sizes; (void)n_in; (void)out_size; (void)ws_size;
    const float* x    = (const float*)d_in[0];
    const float* W_ih = (const float*)d_in[1];
    const float* W_hh = (const float*)d_in[2];
    const float* b_ih = (const float*)d_in[3];
    const float* b_hh = (const float*)d_in[4];
    const float* W_fc = (const float*)d_in[5];
    const float* b_fc = (const float*)d_in[6];
    float* out = (float*)d_out;

    unsigned short* buf = (unsigned short*)d_ws;                 // [T*B][H] bf16: xp -> h (in place)
    int* flags = (int*)((char*)d_ws + (size_t)Tt * Bb * Hh * 2); // 16 ints

    k_init <<<dim3(1),        dim3(64),  0, stream>>>(flags);
    k_xproj<<<dim3(1024, 4),  dim3(256), 0, stream>>>(x, W_ih, b_ih, b_hh, buf);
    k_rnn  <<<dim3(16),       dim3(256), 0, stream>>>(W_hh, buf, flags);
    k_fc   <<<dim3(1024, 2),  dim3(256), 0, stream>>>(buf, W_fc, b_fc, out);
    k_hid  <<<dim3(64),       dim3(512), 0, stream>>>(buf, out + (size_t)Bb * Tt * Oo);
}